// Round 8
// baseline (340.437 us; speedup 1.0000x reference)
//
#include <hip/hip_runtime.h>

#define D_MODEL 2048
#define ADAPTER 64
#define RPB     8           // rows per block
#define THREADS 256
#define NROWS   16384       // 4 * 4096

typedef __attribute__((ext_vector_type(4))) float f32x4;
typedef __attribute__((ext_vector_type(8))) short bf16x8;
typedef __attribute__((ext_vector_type(4))) unsigned short u16x4;
typedef __attribute__((ext_vector_type(8))) unsigned short u16x8;

__device__ __forceinline__ unsigned short f2bf(float f) {
    unsigned int u = __float_as_uint(f);
    u += 0x7fffu + ((u >> 16) & 1u);       // round-to-nearest-even
    return (unsigned short)(u >> 16);
}
__device__ __forceinline__ float bf2f(unsigned short u) {
    return __uint_as_float(((unsigned int)u) << 16);
}

// ---- prep: fold LN weight into down-proj, bf16-ify weights ---------------
// blocks 0..63   : dwl[a][d] = bf16(dw[a][d]*lnw[d]); T[a]=sum(dwl); CC[a]=sum(dw*lnb)+db[a]
// blocks 64..191 : uwb = bf16(uw)
__global__ __launch_bounds__(256)
void prep_weights(const float* __restrict__ dw, const float* __restrict__ lnw,
                  const float* __restrict__ lnb, const float* __restrict__ db,
                  const float* __restrict__ uw,
                  unsigned short* __restrict__ dwl, float* __restrict__ T,
                  float* __restrict__ CC, unsigned short* __restrict__ uwb)
{
    __shared__ float redT[4], redC[4];
    const int b = blockIdx.x;
    const int tid = threadIdx.x;
    if (b < 64) {
        const int a = b;
        const float* dr = dw + a * D_MODEL;
        float tpart = 0.f, cpart = 0.f;
#pragma unroll
        for (int j = 0; j < 2; ++j) {
            const int e = 4 * tid + 1024 * j;
            f32x4 wv = *(const f32x4*)(dr + e);
            f32x4 gv = *(const f32x4*)(lnw + e);
            f32x4 bv = *(const f32x4*)(lnb + e);
            u16x4 o;
#pragma unroll
            for (int k = 0; k < 4; ++k) {
                const unsigned short h = f2bf(wv[k] * gv[k]);
                o[k] = h;
                tpart += bf2f(h);              // match MFMA operand precision
                cpart += wv[k] * bv[k];
            }
            *(u16x4*)(dwl + a * D_MODEL + e) = o;
        }
#pragma unroll
        for (int off = 32; off; off >>= 1) {
            tpart += __shfl_xor(tpart, off, 64);
            cpart += __shfl_xor(cpart, off, 64);
        }
        const int w = tid >> 6, l = tid & 63;
        if (l == 0) { redT[w] = tpart; redC[w] = cpart; }
        __syncthreads();
        if (tid == 0) {
            T[a]  = redT[0] + redT[1] + redT[2] + redT[3];
            CC[a] = redC[0] + redC[1] + redC[2] + redC[3] + db[a];
        }
    } else {
        const int i = 4 * ((b - 64) * 256 + tid);
        f32x4 v = *(const f32x4*)(uw + i);
        u16x4 r;
#pragma unroll
        for (int k = 0; k < 4; ++k) r[k] = f2bf(v[k]);
        *(u16x4*)(uwb + i) = r;
    }
}

// ---- main fused kernel ----------------------------------------------------
// Raw bf16 x lives in swizzled LDS (byte ^= row<<4); LN folded into dwl with
// per-row affine fixup after the MFMA. Rows 8..15 of the MFMA tile duplicate
// rows 0..7 (RPB=8); duplication is self-consistent through H; stores guarded.
__global__ __launch_bounds__(THREADS, 4)
void houlsby_fused(const float* __restrict__ x,
                   const unsigned short* __restrict__ dwl,  // bf16 [64][2048], lnw-folded
                   const float* __restrict__ T,             // [64]
                   const float* __restrict__ CC,            // [64]
                   const unsigned short* __restrict__ uwb,  // bf16 [2048][64]
                   const float* __restrict__ ub,            // [2048]
                   float* __restrict__ out)
{
    __shared__ __align__(16) unsigned short xl[RPB * D_MODEL];   // 32 KB raw bf16 (swizzled)
    __shared__ __align__(16) unsigned short Hl[16][ADAPTER + 8];
    __shared__ float stats_mu[RPB];
    __shared__ float stats_rs[RPB];

    const int tid = threadIdx.x;
    const int w   = tid >> 6;      // wave 0..3
    const int l   = tid & 63;      // lane
    const int rowBase = blockIdx.x * RPB;

    // ---------- Pass A: stream x once: stats + raw bf16 -> swizzled LDS ----------
#pragma unroll
    for (int rr = 0; rr < 2; ++rr) {
        const int row = 2 * w + rr;
        const float* xr = x + (size_t)(rowBase + row) * D_MODEL;
        char* xrow_l = (char*)(xl + row * D_MODEL);
        const int swz = row << 4;
        float s = 0.f, sq = 0.f;
#pragma unroll
        for (int j = 0; j < 8; ++j) {
            f32x4 v = *(const f32x4*)(xr + 4 * l + 256 * j);
            s  += v.x + v.y + v.z + v.w;
            sq += v.x * v.x + v.y * v.y + v.z * v.z + v.w * v.w;
            u16x4 hv;
#pragma unroll
            for (int k = 0; k < 4; ++k) hv[k] = f2bf(v[k]);
            *(u16x4*)(xrow_l + (((4 * l + 256 * j) * 2) ^ swz)) = hv;
        }
#pragma unroll
        for (int off = 32; off; off >>= 1) {
            s  += __shfl_xor(s,  off, 64);
            sq += __shfl_xor(sq, off, 64);
        }
        if (l == 0) {
            const float mu  = s * (1.f / D_MODEL);
            const float var = sq * (1.f / D_MODEL) - mu * mu;
            stats_mu[row] = mu;
            stats_rs[row] = rsqrtf(var + 1e-5f);
        }
    }
    __syncthreads();

    // ---------- Phase 2: down-proj on RAW x (M=8 dup to 16, N=64, K=2048) ----------
    const int m  = l & 15;
    const int g  = l >> 4;
    const int a0 = 16 * w + m;                    // adapter col (all 64 covered)
    const int mrow = m & 7;                       // token row (dup for m>=8)
    const unsigned short* dwr = dwl + a0 * D_MODEL;
    const char* xrow_l = (const char*)(xl + mrow * D_MODEL);
    const int swzm = mrow << 4;

    f32x4 acc = {0.f, 0.f, 0.f, 0.f};
#pragma unroll 8
    for (int ks = 0; ks < 64; ++ks) {
        const int kb = 32 * ks + 8 * g;
        const bf16x8 af = *(const bf16x8*)(xrow_l + ((2 * kb) ^ swzm));  // raw bf16 x
        const bf16x8 bw = *(const bf16x8*)(dwr + kb);                    // L2-hot
        acc = __builtin_amdgcn_mfma_f32_16x16x32_bf16(af, bw, acc, 0, 0, 0);
    }

    // ---------- Phase 3: LN affine fixup + bias + relu -> H (bf16) ----------
    {
        const float Ta = T[a0];
        const float Ca = CC[a0];
#pragma unroll
        for (int r = 0; r < 4; ++r) {
            const int t = (4 * g + r) & 7;
            const float pre = fmaf(-stats_mu[t], Ta, acc[r]);   // S1 - mu*T
            const float h   = fmaxf(fmaf(stats_rs[t], pre, Ca), 0.f);
            Hl[4 * g + r][a0] = f2bf(h);
        }
    }
    __syncthreads();

    // ---------- Phase 4: up-proj, operand-swapped (A=uw, B=H) + residual ----------
    bf16x8 Hf[2];
#pragma unroll
    for (int ks = 0; ks < 2; ++ks)
        Hf[ks] = *(const bf16x8*)(&Hl[m][32 * ks + 8 * g]);

    const int dBase = 512 * w;
    const size_t orow = (size_t)(rowBase + mrow) * D_MODEL;
#pragma unroll 4
    for (int nt = 0; nt < 32; ++nt) {
        const int d0 = dBase + 16 * nt;
        const unsigned short* uwr = uwb + (d0 + m) * ADAPTER;
        const bf16x8 A0 = *(const bf16x8*)(uwr + 8 * g);
        const bf16x8 A1 = *(const bf16x8*)(uwr + 32 + 8 * g);

        f32x4 c = {0.f, 0.f, 0.f, 0.f};
        c = __builtin_amdgcn_mfma_f32_16x16x32_bf16(A0, Hf[0], c, 0, 0, 0);
        c = __builtin_amdgcn_mfma_f32_16x16x32_bf16(A1, Hf[1], c, 0, 0, 0);

        if (m < 8) {                                   // lanes m>=8 hold dup outputs
            const int dcol = d0 + 4 * g;
            const f32x4 ubv  = *(const f32x4*)(ub + dcol);
            const u16x4 xres = *(const u16x4*)(xrow_l + ((2 * dcol) ^ swzm));
            f32x4 o;
#pragma unroll
            for (int r = 0; r < 4; ++r)
                o[r] = bf2f(xres[r]) + c[r] + ubv[r];
            *(f32x4*)(out + orow + dcol) = o;
        }
    }
}

extern "C" void kernel_launch(void* const* d_in, const int* in_sizes, int n_in,
                              void* d_out, int out_size, void* d_ws, size_t ws_size,
                              hipStream_t stream) {
    const float* x   = (const float*)d_in[0];
    const float* lnw = (const float*)d_in[1];
    const float* lnb = (const float*)d_in[2];
    const float* dw  = (const float*)d_in[3];
    const float* db  = (const float*)d_in[4];
    const float* uw  = (const float*)d_in[5];
    const float* ub  = (const float*)d_in[6];
    float* out = (float*)d_out;

    // workspace layout
    unsigned short* dwl = (unsigned short*)d_ws;                          // 256 KiB
    float*          Tp  = (float*)((char*)d_ws + 262144);                 // 256 B
    float*          CCp = (float*)((char*)d_ws + 262144 + 256);           // 256 B
    unsigned short* uwb = (unsigned short*)((char*)d_ws + 262144 + 512);  // 256 KiB

    prep_weights<<<dim3(192), dim3(256), 0, stream>>>(dw, lnw, lnb, db, uw,
                                                      dwl, Tp, CCp, uwb);

    dim3 grid(NROWS / RPB);   // 2048 blocks, 4 per CU
    dim3 block(THREADS);
    houlsby_fused<<<grid, block, 0, stream>>>(x, dwl, Tp, CCp, uwb, ub, out);
}